// Round 5
// baseline (358.832 us; speedup 1.0000x reference)
//
#include <hip/hip_runtime.h>
#include <math.h>

// v5: 16 points per BLOCK, 4 cooperating waves (256 thr). Each wave hoists a
// QUARTER of each W2 fragment layout (32+32 VGPRs) -> ~90 persistent regs,
// peak ~160 << 256: no spills (v4 failed: launch_bounds(128,2) forced a
// 128v/128a split -> 85 MB scratch traffic). Solve: 16 lanes/point, one row
// per lane (R[17]), shfl pivot broadcast; each wave solves its own 4 points.
// dv = G^{-1} aug,  G = A A^T + I,  aug = sum_n W1[i][n] (h_n^2-1) r_n.

typedef _Float16 f16;
typedef _Float16 f16x4 __attribute__((ext_vector_type(4)));
typedef _Float16 f16x8 __attribute__((ext_vector_type(8)));
typedef float f32x2 __attribute__((ext_vector_type(2)));
typedef float f32x4 __attribute__((ext_vector_type(4)));
typedef float f32x16 __attribute__((ext_vector_type(16)));

#define SAG_P 392   // f16 point stride (A/G row stride 24)
#define SZ_P 36     // f32
#define SH_P 72     // f16
#define SW_P 20     // f32

__device__ __forceinline__ float fastTanh(float x) {
    float e = exp2f(x * 2.885390081777927f);
    return 1.0f - 2.0f * __builtin_amdgcn_rcpf(1.0f + e);
}

__global__ __launch_bounds__(256, 1)
void geo_kernel(const float* __restrict__ zin, const float* __restrict__ tg,
                const float* __restrict__ W1g, const float* __restrict__ b1g,
                const float* __restrict__ W2g, const float* __restrict__ b2g,
                const int* __restrict__ nsg, float* __restrict__ outg, int B)
{
    __shared__ __align__(16) f16   sAG[16 * SAG_P];  // A, then G (aug col at 16)
    __shared__ __align__(16) f16   sHT[16 * SH_P];   // h, later t
    __shared__ __align__(16) float sZI[16 * SZ_P];
    __shared__ __align__(16) float sWw[16 * SW_P];
    __shared__ __align__(16) float sKV[16 * SW_P];

    const int tid = threadIdx.x;
    const int w = tid >> 6;               // wave id 0..3
    const int l = tid & 63;
    const int i16 = l & 15, q4 = l >> 4, h2 = l >> 5, sc = q4 & 1;

    // ---------------- hoisted weights (QUARTER per wave) ----------------
    f16x8 w2a[4][2];   // A-stage B-frag, tiles 4w+t' : W2[n=8q4+j+32ch][e=i16+16(4w+t')]
    #pragma unroll
    for (int t = 0; t < 4; ++t)
        #pragma unroll
        for (int ch = 0; ch < 2; ++ch)
            #pragma unroll
            for (int j = 0; j < 8; ++j)
                w2a[t][ch][j] = (f16)W2g[(8*q4 + j + 32*ch)*256 + i16 + 16*(4*w + t)];

    f16x8 w2r[8];      // r-stage B-frag, tile w : W2[n=i16+16w][e=8q4+j+32ch]
    #pragma unroll
    for (int ch = 0; ch < 8; ++ch)
        #pragma unroll
        for (int j = 0; j < 8; ++j)
            w2r[ch][j] = (f16)W2g[(i16 + 16*w)*256 + 8*q4 + j + 32*ch];

    f16x8 w1h;         // H-stage B-frag (K zero-padded 16->32), tile w
    #pragma unroll
    for (int j = 0; j < 8; ++j) {
        int k = 8*q4 + j;
        w1h[j] = (k < 16) ? (f16)W1g[k*64 + i16 + 16*w] : (f16)0.0f;
    }

    f16x8 w1q[2];      // q-stage B-frag (wave 0): W1[i=i16][n=8q4+j+32ch]
    if (w == 0) {
        #pragma unroll
        for (int ch = 0; ch < 2; ++ch)
            #pragma unroll
            for (int j = 0; j < 8; ++j)
                w1q[ch][j] = (f16)W1g[i16*64 + 8*q4 + j + 32*ch];
    }

    float b2v[4];
    #pragma unroll
    for (int t = 0; t < 4; ++t) b2v[t] = b2g[i16 + 16*(4*w + t)];
    const float b1v = b1g[i16 + 16*w];

    // ---------------- RK4 state: thread owns point tid>>4, vals 2g,2g+1 ----
    const int pb = blockIdx.x * 16;
    const int p_cmb = tid >> 4;           // == 4w + q4
    const int g16 = tid & 15;
    f32x2 zc, ar;
    {
        int pg = (pb + p_cmb < B) ? (pb + p_cmb) : (B - 1);
        zc = *(const f32x2*)&zin[pg*32 + 2*g16];
        *(f32x2*)&sZI[p_cmb*SZ_P + 2*g16] = zc;
    }
    __syncthreads();

    const float tv = tg[0];
    const int nst = nsg[0];
    const float dt = tv / (float)nst;

    #pragma unroll 1
    for (int st = 0; st < nst; ++st) {
        #pragma unroll 1
        for (int s = 0; s < 4; ++s) {
            // ---- per-eval x,v loads (lane p = i16) ----
            float vreg[16];
            f16x8 xf;
            {
                f32x4 xa = *(const f32x4*)&sZI[i16*SZ_P + 8*sc];
                f32x4 xb = *(const f32x4*)&sZI[i16*SZ_P + 8*sc + 4];
                #pragma unroll
                for (int j = 0; j < 4; ++j) { xf[j] = (f16)xa[j]; xf[4+j] = (f16)xb[j]; }
                #pragma unroll
                for (int m = 0; m < 4; ++m) {
                    f32x4 v4 = *(const f32x4*)&sZI[i16*SZ_P + 16 + 4*m];
                    #pragma unroll
                    for (int j = 0; j < 4; ++j) vreg[4*m + j] = v4[j];
                }
            }
            // ======== H-stage (1 tile per wave) ========
            float dreg[4];
            {
                f32x4 hc = {0.f, 0.f, 0.f, 0.f};
                hc = __builtin_amdgcn_mfma_f32_16x16x32_f16(xf, w1h, hc, 0, 0, 0);
                #pragma unroll
                for (int reg = 0; reg < 4; ++reg) {
                    float hv = fastTanh(hc[reg] + b1v);
                    dreg[reg] = hv*hv - 1.0f;
                    sHT[(4*q4 + reg)*SH_P + i16 + 16*w] = (f16)hv;
                }
            }
            __syncthreads();   // B1: h ready
            // ======== A-stage (4 e-tiles per wave) ========
            {
                f16x8 hf0 = *(const f16x8*)&sHT[i16*SH_P + 8*q4];
                f16x8 hf1 = *(const f16x8*)&sHT[i16*SH_P + 8*q4 + 32];
                #pragma unroll
                for (int t = 0; t < 4; ++t) {
                    f32x4 ac = {0.f, 0.f, 0.f, 0.f};
                    ac = __builtin_amdgcn_mfma_f32_16x16x32_f16(hf0, w2a[t][0], ac, 0, 0, 0);
                    ac = __builtin_amdgcn_mfma_f32_16x16x32_f16(hf1, w2a[t][1], ac, 0, 0, 0);
                    #pragma unroll
                    for (int reg = 0; reg < 4; ++reg)
                        sAG[(4*q4 + reg)*SAG_P + 24*(4*w + t) + i16] = (f16)(ac[reg] + b2v[t]);
                }
            }
            __syncthreads();   // B2: A ready
            // ======== w-stage (redundant on all waves): w_c = sum_a v_a A[a][c] ========
            {
                float w4[4] = {0.f, 0.f, 0.f, 0.f};
                #pragma unroll
                for (int a = 0; a < 16; ++a) {
                    f16x4 av = *(const f16x4*)&sAG[i16*SAG_P + 24*a + 4*q4];
                    #pragma unroll
                    for (int u = 0; u < 4; ++u) w4[u] += vreg[a] * (float)av[u];
                }
                f32x4 wv4 = {w4[0], w4[1], w4[2], w4[3]};
                *(f32x4*)&sWw[i16*SW_P + 4*q4] = wv4;
            }
            __syncthreads();   // B3: w ready; all A reads done (G may overwrite)
            // ======== AAT (2 pair-MFMAs per wave) -> G over A region ========
            #pragma unroll
            for (int u0 = 0; u0 < 2; ++u0) {
                int u = 2*w + u0;
                f16x8 af = *(const f16x8*)&sAG[(2*u + sc)*SAG_P + 24*i16 + 8*h2];
                f32x16 gz = {0.0f};
                f32x16 gacc = __builtin_amdgcn_mfma_f32_32x32x16_f16(af, af, gz, 0, 0, 0);
                #pragma unroll
                for (int rr = 0; rr < 8; ++rr) {
                    int a_ = (rr & 3) + 8*(rr >> 2) + 4*h2;
                    float gv = gacc[rr + 8*sc] + ((a_ == i16) ? 1.0f : 0.0f);
                    sAG[(2*u + sc)*SAG_P + 24*a_ + i16] = (f16)gv;
                }
            }
            // ======== r-stage (1 n-tile per wave): R = (v (x) w) @ W2^T ========
            {
                f32x4 racc = {0.f, 0.f, 0.f, 0.f};
                float wv[8];
                {
                    f32x4 wa = *(const f32x4*)&sWw[i16*SW_P + 8*sc];
                    f32x4 wb = *(const f32x4*)&sWw[i16*SW_P + 8*sc + 4];
                    #pragma unroll
                    for (int j = 0; j < 4; ++j) { wv[j] = wa[j]; wv[4+j] = wb[j]; }
                }
                #pragma unroll
                for (int ch = 0; ch < 8; ++ch) {
                    float vv = vreg[2*ch + (q4 >> 1)];
                    f16x8 uf;
                    #pragma unroll
                    for (int j = 0; j < 8; ++j) uf[j] = (f16)(vv * wv[j]);
                    racc = __builtin_amdgcn_mfma_f32_16x16x32_f16(uf, w2r[ch], racc, 0, 0, 0);
                }
                #pragma unroll
                for (int reg = 0; reg < 4; ++reg)
                    sHT[(4*q4 + reg)*SH_P + i16 + 16*w] = (f16)(dreg[reg] * racc[reg]);
            }
            __syncthreads();   // B4: t ready, G ready
            // ======== q-stage (wave 0): aug = T @ W1^T -> sAG[p][i][16] ========
            if (w == 0) {
                f16x8 tf0 = *(const f16x8*)&sHT[i16*SH_P + 8*q4];
                f16x8 tf1 = *(const f16x8*)&sHT[i16*SH_P + 8*q4 + 32];
                f32x4 qa = {0.f, 0.f, 0.f, 0.f};
                qa = __builtin_amdgcn_mfma_f32_16x16x32_f16(tf0, w1q[0], qa, 0, 0, 0);
                qa = __builtin_amdgcn_mfma_f32_16x16x32_f16(tf1, w1q[1], qa, 0, 0, 0);
                #pragma unroll
                for (int reg = 0; reg < 4; ++reg)
                    sAG[(4*q4 + reg)*SAG_P + 24*i16 + 16] = (f16)qa[reg];
            }
            __syncthreads();   // B5: aug ready
            // ======== solve G y = aug; wave w owns points 4w+q4, lane i16 = row ========
            {
                const int psl = 4*w + q4;
                float R[17];
                {
                    const f16* rp = &sAG[psl*SAG_P + 24*i16];
                    f16x8 ra = *(const f16x8*)&rp[0];
                    f16x8 rb = *(const f16x8*)&rp[8];
                    #pragma unroll
                    for (int j = 0; j < 8; ++j) { R[j] = (float)ra[j]; R[8+j] = (float)rb[j]; }
                    R[16] = (float)rp[16];
                }
                // forward elimination (row per lane, pivot row broadcast in 16-groups)
                #pragma unroll
                for (int k = 0; k < 16; ++k) {
                    const int src = (l & 48) | k;
                    float pvk = __shfl(R[k], src);
                    float pinv = __builtin_amdgcn_rcpf(pvk);
                    float f = (i16 > k) ? (R[k] * pinv) : 0.0f;
                    #pragma unroll
                    for (int j = k + 1; j < 17; ++j) {
                        float pvj = __shfl(R[j], src);
                        R[j] -= f * pvj;
                    }
                }
                // back substitution
                float y = 0.0f;
                #pragma unroll
                for (int k = 15; k >= 0; --k) {
                    float cand = R[16] * __builtin_amdgcn_rcpf(R[k]);
                    float yk = __shfl(cand, (l & 48) | k);
                    if (i16 == k) y = yk;
                    if (i16 < k) R[16] -= R[k] * yk;
                }
                sKV[psl*SW_P + i16] = y;
            }
            // (no barrier: combine reads only this wave's points; DS in-order per wave)
            // ======== RK4 combine (thread: p=p_cmb, vals 2g16..2g16+1) ========
            {
                f32x2 kk;
                if (g16 < 8) kk = *(const f32x2*)&sZI[p_cmb*SZ_P + 16 + 2*g16];
                else         kk = *(const f32x2*)&sKV[p_cmb*SW_P + 2*(g16 - 8)];
                if (s == 0) ar = kk;
                else {
                    float wgt = (s == 3) ? 1.0f : 2.0f;
                    ar.x += wgt * kk.x; ar.y += wgt * kk.y;
                }
                f32x2 zi;
                if (s < 3) {
                    float alpha = (s < 2) ? (0.5f * dt) : dt;
                    zi.x = zc.x + alpha * kk.x; zi.y = zc.y + alpha * kk.y;
                } else {
                    float c6 = dt / 6.0f;
                    zc.x += c6 * ar.x; zc.y += c6 * ar.y;
                    zi = zc;
                }
                *(f32x2*)&sZI[p_cmb*SZ_P + 2*g16] = zi;
            }
            __syncthreads();   // B6: zI ready for next eval
        }
    }
    if (pb + p_cmb < B)
        *(f32x2*)&outg[(pb + p_cmb)*32 + 2*g16] = zc;
}

extern "C" void kernel_launch(void* const* d_in, const int* in_sizes, int n_in,
                              void* d_out, int out_size, void* d_ws, size_t ws_size,
                              hipStream_t stream) {
    (void)n_in; (void)d_ws; (void)ws_size; (void)out_size;
    const float* z  = (const float*)d_in[0];
    const float* t  = (const float*)d_in[1];
    const float* W1 = (const float*)d_in[2];
    const float* b1 = (const float*)d_in[3];
    const float* W2 = (const float*)d_in[4];
    const float* b2 = (const float*)d_in[5];
    const int*   ns = (const int*)d_in[6];
    float* out = (float*)d_out;
    const int B = in_sizes[0] / 32;
    int grid = (B + 15) / 16;
    hipLaunchKernelGGL(geo_kernel, dim3(grid), dim3(256), 0, stream,
                       z, t, W1, b1, W2, b2, ns, out, B);
}

// Round 7
// 269.242 us; speedup vs baseline: 1.3328x; 1.3328x over previous
//
#include <hip/hip_runtime.h>
#include <math.h>

// v6b: DS-op diet (v6 + compile fix: cvt_pkrtz returns __fp16x2, bit-cast it).
// 16 pts/block, 4 waves. Weight frags quartered per wave. MFMA operand order
// swapped (A=weight^T, B=acts) so C-layout gives each lane 4 contiguous
// elements of ONE point -> b64 epilogue writes. w from A-epi registers
// (cross-wave partial sum in LDS). G written transposed (G symmetric).
// Solve: Gauss-Jordan, row-per-lane, pivot-suffix broadcast via ds_swizzle
// (compile-time imm) with f16-packed pairs; diag f32; y_i local (no back-sub).
// 4 barriers/eval.

typedef _Float16 f16;
typedef _Float16 f16x2 __attribute__((ext_vector_type(2)));
typedef _Float16 f16x4 __attribute__((ext_vector_type(4)));
typedef _Float16 f16x8 __attribute__((ext_vector_type(8)));
typedef __fp16 h16x2 __attribute__((ext_vector_type(2)));   // builtin return type
typedef float f32x2 __attribute__((ext_vector_type(2)));
typedef float f32x4 __attribute__((ext_vector_type(4)));
typedef float f32x16 __attribute__((ext_vector_type(16)));

#define SAG_P 392   // f16 point stride; row stride 24, aug col at 16
#define SZ_P  36    // f32
#define SH_P  72    // f16
#define SW_P  20    // f32
#define SWP_C 20    // f32 stride of sWp per (wave,point)

__device__ __forceinline__ float fastTanh(float x) {
    float e = exp2f(x * 2.885390081777927f);
    return 1.0f - 2.0f * __builtin_amdgcn_rcpf(1.0f + e);
}

// broadcast lane K of each 16-lane group (BitMode swizzle: or_mask=K, and=0x10 kept)
template<int K>
__device__ __forceinline__ float bcf(float x) {
    int v = __builtin_amdgcn_ds_swizzle(__builtin_bit_cast(int, x), 0x10 | (K << 5));
    return __builtin_bit_cast(float, v);
}
template<int K>
__device__ __forceinline__ int bci(int x) {
    return __builtin_amdgcn_ds_swizzle(x, 0x10 | (K << 5));
}

// Gauss-Jordan elimination, row-per-lane (16 lanes/point). Updates cols > K
// of every row != K. Pivot suffix broadcast f16-packed; diagonal f32.
template<int K>
__device__ __forceinline__ void fe_all(float (&R)[17], const int i16, float &myinv) {
    if constexpr (K < 16) {
        float pvk = bcf<K>(R[K]);
        float pinv = __builtin_amdgcn_rcpf(pvk);
        if (i16 == K) myinv = pinv;
        float f = (i16 == K) ? 0.0f : R[K] * pinv;
        #pragma unroll
        for (int j = K + 1; j + 1 <= 16; j += 2) {
            h16x2 pk = __builtin_amdgcn_cvt_pkrtz(R[j], R[j + 1]);
            int pi = bci<K>(__builtin_bit_cast(int, pk));
            f16x2 pv = __builtin_bit_cast(f16x2, pi);
            R[j]     -= f * (float)pv.x;
            R[j + 1] -= f * (float)pv.y;
        }
        if constexpr ((K & 1) == 1) {   // odd K: suffix length odd, tail j=16
            float p16 = bcf<K>(R[16]);
            R[16] -= f * p16;
        }
        fe_all<K + 1>(R, i16, myinv);
    }
}

__global__ __launch_bounds__(256, 1)
void geo_kernel(const float* __restrict__ zin, const float* __restrict__ tg,
                const float* __restrict__ W1g, const float* __restrict__ b1g,
                const float* __restrict__ W2g, const float* __restrict__ b2g,
                const int* __restrict__ nsg, float* __restrict__ outg, int B)
{
    __shared__ __align__(16) f16   sAG[16 * SAG_P];      // A, then G (+aug)
    __shared__ __align__(16) f16   sHT[16 * SH_P];       // h, later t
    __shared__ __align__(16) float sZI[16 * SZ_P];
    __shared__ __align__(16) float sKV[16 * SW_P];
    __shared__ __align__(16) float sWp[4 * 16 * SWP_C];  // w partials per wave

    const int tid = threadIdx.x;
    const int w = tid >> 6;
    const int l = tid & 63;
    const int i16 = l & 15, q4 = l >> 4, h2 = l >> 5, sc = q4 & 1;

    // ---------------- hoisted weight fragments (quarter per wave) ----------
    // A-stage A-operand: W2^T[e = i16+16*(4w+t)][k = 8q4+j+32ch]
    f16x8 w2a[4][2];
    #pragma unroll
    for (int t = 0; t < 4; ++t)
        #pragma unroll
        for (int ch = 0; ch < 2; ++ch)
            #pragma unroll
            for (int j = 0; j < 8; ++j)
                w2a[t][ch][j] = (f16)W2g[(8*q4 + j + 32*ch)*256 + i16 + 16*(4*w + t)];

    // r-stage A-operand: W2[n = i16+16w][e = 8q4+j+32ch]
    f16x8 w2r[8];
    #pragma unroll
    for (int ch = 0; ch < 8; ++ch)
        #pragma unroll
        for (int j = 0; j < 8; ++j)
            w2r[ch][j] = (f16)W2g[(i16 + 16*w)*256 + 8*q4 + j + 32*ch];

    // H-stage A-operand: W1^T[n = i16+16w][x = 8q4+j], zero-pad k>=16
    f16x8 w1h;
    #pragma unroll
    for (int j = 0; j < 8; ++j) {
        int k = 8*q4 + j;
        w1h[j] = (k < 16) ? (f16)W1g[k*64 + i16 + 16*w] : (f16)0.0f;
    }

    // q-stage A-operand (all waves): W1[i = i16][n = 8q4+j+32ch]
    f16x8 w1q[2];
    #pragma unroll
    for (int ch = 0; ch < 2; ++ch)
        #pragma unroll
        for (int j = 0; j < 8; ++j)
            w1q[ch][j] = (f16)W1g[i16*64 + 8*q4 + j + 32*ch];

    float b2v[4][4];   // b2[e = 16*(4w+t) + 4q4+reg]
    #pragma unroll
    for (int t = 0; t < 4; ++t)
        #pragma unroll
        for (int reg = 0; reg < 4; ++reg)
            b2v[t][reg] = b2g[16*(4*w + t) + 4*q4 + reg];
    float b1v[4];      // b1[n = 16w + 4q4+reg]
    #pragma unroll
    for (int reg = 0; reg < 4; ++reg) b1v[reg] = b1g[16*w + 4*q4 + reg];

    // ---------------- RK4 state: thread owns point tid>>4, vals 2g16.. ----
    const int pb = blockIdx.x * 16;
    const int p_cmb = tid >> 4;            // == 4w + q4
    const int g16 = tid & 15;
    f32x2 zc, ar;
    {
        int pg = (pb + p_cmb < B) ? (pb + p_cmb) : (B - 1);
        zc = *(const f32x2*)&zin[pg*32 + 2*g16];
        *(f32x2*)&sZI[p_cmb*SZ_P + 2*g16] = zc;
    }
    __syncthreads();

    const float tv = tg[0];
    const int nst = nsg[0];
    const float dt = tv / (float)nst;

    #pragma unroll 1
    for (int st = 0; st < nst; ++st) {
        #pragma unroll 1
        for (int s = 0; s < 4; ++s) {
            // ---- per-eval x,v loads (lane p = i16) ----
            float vreg[16];
            f16x8 xf;
            {
                f32x4 xa = *(const f32x4*)&sZI[i16*SZ_P + 8*sc];
                f32x4 xb = *(const f32x4*)&sZI[i16*SZ_P + 8*sc + 4];
                bool xz = (q4 >= 2);
                #pragma unroll
                for (int j = 0; j < 4; ++j) {
                    xf[j]     = xz ? (f16)0.0f : (f16)xa[j];
                    xf[4 + j] = xz ? (f16)0.0f : (f16)xb[j];
                }
                #pragma unroll
                for (int m = 0; m < 4; ++m) {
                    f32x4 v4 = *(const f32x4*)&sZI[i16*SZ_P + 16 + 4*m];
                    #pragma unroll
                    for (int j = 0; j < 4; ++j) vreg[4*m + j] = v4[j];
                }
            }
            // ======== H: C[n-tile][point] = W1^T X; lane: point i16, n=16w+4q4+reg ====
            float dreg[4];
            {
                f32x4 hc = {0.f, 0.f, 0.f, 0.f};
                hc = __builtin_amdgcn_mfma_f32_16x16x32_f16(w1h, xf, hc, 0, 0, 0);
                f16x4 hv4;
                #pragma unroll
                for (int reg = 0; reg < 4; ++reg) {
                    float hv = fastTanh(hc[reg] + b1v[reg]);
                    dreg[reg] = hv*hv - 1.0f;
                    hv4[reg] = (f16)hv;
                }
                *(f16x4*)&sHT[i16*SH_P + 16*w + 4*q4] = hv4;
            }
            __syncthreads();   // B1: h ready
            // ======== A: C[e-tile][point]; lane: point i16, e=16(4w+t)+4q4+reg ======
            // + w partials from epilogue registers: pw[c=4q4+reg] = sum_t v[4w+t]*A
            {
                f16x8 hf0 = *(const f16x8*)&sHT[i16*SH_P + 8*q4];
                f16x8 hf1 = *(const f16x8*)&sHT[i16*SH_P + 8*q4 + 32];
                float pw[4] = {0.f, 0.f, 0.f, 0.f};
                #pragma unroll
                for (int t = 0; t < 4; ++t) {
                    f32x4 ac = {0.f, 0.f, 0.f, 0.f};
                    ac = __builtin_amdgcn_mfma_f32_16x16x32_f16(w2a[t][0], hf0, ac, 0, 0, 0);
                    ac = __builtin_amdgcn_mfma_f32_16x16x32_f16(w2a[t][1], hf1, ac, 0, 0, 0);
                    f16x4 av;
                    float vv = vreg[4*w + t];
                    #pragma unroll
                    for (int reg = 0; reg < 4; ++reg) {
                        float aval = ac[reg] + b2v[t][reg];
                        av[reg] = (f16)aval;
                        pw[reg] += vv * aval;
                    }
                    *(f16x4*)&sAG[i16*SAG_P + 24*(4*w + t) + 4*q4] = av;
                }
                f32x4 pwv = {pw[0], pw[1], pw[2], pw[3]};
                *(f32x4*)&sWp[(w*16 + i16)*SWP_C + 4*q4] = pwv;
            }
            __syncthreads();   // B2: A + w partials ready
            // ======== AAT (2 pair-MFMAs/wave) -> G^T over A region (G symmetric) ====
            #pragma unroll
            for (int u0 = 0; u0 < 2; ++u0) {
                int u = 2*w + u0;
                int pt = 2*u + sc;
                f16x8 af = *(const f16x8*)&sAG[pt*SAG_P + 24*i16 + 8*h2];
                f32x16 gz = {0.0f};
                f32x16 gacc = __builtin_amdgcn_mfma_f32_32x32x16_f16(af, af, gz, 0, 0, 0);
                f16x4 g0, g1;
                #pragma unroll
                for (int rr = 0; rr < 4; ++rr) {
                    int a0 = 4*h2 + rr;
                    int a1 = 8 + 4*h2 + rr;
                    g0[rr] = (f16)(gacc[rr + 8*sc]     + ((i16 == a0) ? 1.0f : 0.0f));
                    g1[rr] = (f16)(gacc[rr + 4 + 8*sc] + ((i16 == a1) ? 1.0f : 0.0f));
                }
                *(f16x4*)&sAG[pt*SAG_P + 24*i16 + 4*h2]     = g0;
                *(f16x4*)&sAG[pt*SAG_P + 24*i16 + 8 + 4*h2] = g1;
            }
            // ======== r: C[n-tile][point] = W2 U; lane: point i16, n=16w+4q4+reg ====
            {
                float wv[8];
                {
                    f32x4 s0 = *(const f32x4*)&sWp[(0*16 + i16)*SWP_C + 8*sc];
                    f32x4 s1 = *(const f32x4*)&sWp[(1*16 + i16)*SWP_C + 8*sc];
                    f32x4 s2 = *(const f32x4*)&sWp[(2*16 + i16)*SWP_C + 8*sc];
                    f32x4 s3 = *(const f32x4*)&sWp[(3*16 + i16)*SWP_C + 8*sc];
                    f32x4 t0 = *(const f32x4*)&sWp[(0*16 + i16)*SWP_C + 8*sc + 4];
                    f32x4 t1 = *(const f32x4*)&sWp[(1*16 + i16)*SWP_C + 8*sc + 4];
                    f32x4 t2 = *(const f32x4*)&sWp[(2*16 + i16)*SWP_C + 8*sc + 4];
                    f32x4 t3 = *(const f32x4*)&sWp[(3*16 + i16)*SWP_C + 8*sc + 4];
                    #pragma unroll
                    for (int j = 0; j < 4; ++j) {
                        wv[j]     = s0[j] + s1[j] + s2[j] + s3[j];
                        wv[4 + j] = t0[j] + t1[j] + t2[j] + t3[j];
                    }
                }
                f32x4 racc = {0.f, 0.f, 0.f, 0.f};
                #pragma unroll
                for (int ch = 0; ch < 8; ++ch) {
                    float vv = vreg[2*ch + (q4 >> 1)];
                    f16x8 uf;
                    #pragma unroll
                    for (int j = 0; j < 8; ++j) uf[j] = (f16)(vv * wv[j]);
                    racc = __builtin_amdgcn_mfma_f32_16x16x32_f16(w2r[ch], uf, racc, 0, 0, 0);
                }
                f16x4 tv4;
                #pragma unroll
                for (int reg = 0; reg < 4; ++reg) tv4[reg] = (f16)(dreg[reg] * racc[reg]);
                *(f16x4*)&sHT[i16*SH_P + 16*w + 4*q4] = tv4;   // t overwrites h
            }
            __syncthreads();   // B4: t ready (G/aug are wave-private from here)
            // ======== q (per wave, own 4 points): aug_i = sum_n W1[i][n] t_n ========
            {
                int ptq = 4*w + (i16 & 3);
                f16x8 tb0 = *(const f16x8*)&sHT[ptq*SH_P + 8*q4];
                f16x8 tb1 = *(const f16x8*)&sHT[ptq*SH_P + 8*q4 + 32];
                f32x4 qa = {0.f, 0.f, 0.f, 0.f};
                qa = __builtin_amdgcn_mfma_f32_16x16x32_f16(w1q[0], tb0, qa, 0, 0, 0);
                qa = __builtin_amdgcn_mfma_f32_16x16x32_f16(w1q[1], tb1, qa, 0, 0, 0);
                if (i16 < 4) {
                    #pragma unroll
                    for (int reg = 0; reg < 4; ++reg)
                        sAG[(4*w + i16)*SAG_P + 24*(4*q4 + reg) + 16] = (f16)qa[reg];
                }
            }
            // ======== solve G y = aug; point 4w+q4, lane i16 = row (GJ, no BS) =====
            {
                const int psl = 4*w + q4;
                float R[17];
                {
                    const f16* rp = &sAG[psl*SAG_P + 24*i16];
                    f16x8 ra = *(const f16x8*)&rp[0];
                    f16x8 rb = *(const f16x8*)&rp[8];
                    #pragma unroll
                    for (int j = 0; j < 8; ++j) { R[j] = (float)ra[j]; R[8+j] = (float)rb[j]; }
                    R[16] = (float)rp[16];
                }
                float myinv = 1.0f;
                fe_all<0>(R, i16, myinv);
                sKV[psl*SW_P + i16] = R[16] * myinv;
            }
            // (no barrier: combine reads only this wave's points; DS in-order)
            // ======== RK4 combine ========
            {
                f32x2 kk;
                if (g16 < 8) kk = *(const f32x2*)&sZI[p_cmb*SZ_P + 16 + 2*g16];
                else         kk = *(const f32x2*)&sKV[p_cmb*SW_P + 2*(g16 - 8)];
                if (s == 0) ar = kk;
                else {
                    float wgt = (s == 3) ? 1.0f : 2.0f;
                    ar.x += wgt * kk.x; ar.y += wgt * kk.y;
                }
                f32x2 zi;
                if (s < 3) {
                    float alpha = (s < 2) ? (0.5f * dt) : dt;
                    zi.x = zc.x + alpha * kk.x; zi.y = zc.y + alpha * kk.y;
                } else {
                    float c6 = dt / 6.0f;
                    zc.x += c6 * ar.x; zc.y += c6 * ar.y;
                    zi = zc;
                }
                *(f32x2*)&sZI[p_cmb*SZ_P + 2*g16] = zi;
            }
            __syncthreads();   // B6: zI ready for next eval
        }
    }
    if (pb + p_cmb < B)
        *(f32x2*)&outg[(pb + p_cmb)*32 + 2*g16] = zc;
}

extern "C" void kernel_launch(void* const* d_in, const int* in_sizes, int n_in,
                              void* d_out, int out_size, void* d_ws, size_t ws_size,
                              hipStream_t stream) {
    (void)n_in; (void)d_ws; (void)ws_size; (void)out_size;
    const float* z  = (const float*)d_in[0];
    const float* t  = (const float*)d_in[1];
    const float* W1 = (const float*)d_in[2];
    const float* b1 = (const float*)d_in[3];
    const float* W2 = (const float*)d_in[4];
    const float* b2 = (const float*)d_in[5];
    const int*   ns = (const int*)d_in[6];
    float* out = (float*)d_out;
    const int B = in_sizes[0] / 32;
    int grid = (B + 15) / 16;
    hipLaunchKernelGGL(geo_kernel, dim3(grid), dim3(256), 0, stream,
                       z, t, W1, b1, W2, b2, ns, out, B);
}

// Round 8
// 264.004 us; speedup vs baseline: 1.3592x; 1.0198x over previous
//
#include <hip/hip_runtime.h>
#include <math.h>

// v7: VALU diet on v6b. (1) solve FE in pure f32 ds_swizzle broadcasts
// (no f16 pack/unpack chains; 152 swizzles+FMAs, shorter serial chain,
// exact f32 pivots). (2) uf built with packed v_pk_mul_f16. (3) all f32->f16
// epilogues via cvt_pkrtz pairs. Structure/barriers/weight frags = v6b.

typedef _Float16 f16;
typedef _Float16 f16x2 __attribute__((ext_vector_type(2)));
typedef _Float16 f16x4 __attribute__((ext_vector_type(4)));
typedef _Float16 f16x8 __attribute__((ext_vector_type(8)));
typedef __fp16 h16x2 __attribute__((ext_vector_type(2)));   // builtin return type
typedef float f32x2 __attribute__((ext_vector_type(2)));
typedef float f32x4 __attribute__((ext_vector_type(4)));
typedef float f32x16 __attribute__((ext_vector_type(16)));

#define SAG_P 392   // f16 point stride; row stride 24, aug col at 16
#define SZ_P  36    // f32
#define SH_P  72    // f16
#define SW_P  20    // f32
#define SWP_C 20    // f32 stride of sWp per (wave,point)

__device__ __forceinline__ float fastTanh(float x) {
    float e = exp2f(x * 2.885390081777927f);
    return 1.0f - 2.0f * __builtin_amdgcn_rcpf(1.0f + e);
}

__device__ __forceinline__ f16x2 pk2(float a, float b) {
    h16x2 p = __builtin_amdgcn_cvt_pkrtz(a, b);
    return __builtin_bit_cast(f16x2, p);
}

typedef union { f16x4 v4; f16x2 v2[2]; } u16x4;
typedef union { f16x8 v8; f16x2 v2[4]; int i32[4]; } u16x8;

// broadcast lane K of each 16-lane group (BitMode swizzle: and=0x10, or=K)
template<int K>
__device__ __forceinline__ float bcf(float x) {
    int v = __builtin_amdgcn_ds_swizzle(__builtin_bit_cast(int, x), 0x10 | (K << 5));
    return __builtin_bit_cast(float, v);
}

// Gauss-Jordan elimination, row-per-lane (16 lanes/point), pure f32 swizzles.
template<int K>
__device__ __forceinline__ void fe_all(float (&R)[17], const int i16, float &myinv) {
    if constexpr (K < 16) {
        float pvk = bcf<K>(R[K]);
        float pinv = __builtin_amdgcn_rcpf(pvk);
        if (i16 == K) myinv = pinv;
        float f = (i16 == K) ? 0.0f : R[K] * pinv;
        #pragma unroll
        for (int j = K + 1; j <= 16; ++j) {
            float pv = bcf<K>(R[j]);
            R[j] -= f * pv;
        }
        fe_all<K + 1>(R, i16, myinv);
    }
}

__global__ __launch_bounds__(256, 1)
void geo_kernel(const float* __restrict__ zin, const float* __restrict__ tg,
                const float* __restrict__ W1g, const float* __restrict__ b1g,
                const float* __restrict__ W2g, const float* __restrict__ b2g,
                const int* __restrict__ nsg, float* __restrict__ outg, int B)
{
    __shared__ __align__(16) f16   sAG[16 * SAG_P];      // A, then G (+aug)
    __shared__ __align__(16) f16   sHT[16 * SH_P];       // h, later t
    __shared__ __align__(16) float sZI[16 * SZ_P];
    __shared__ __align__(16) float sKV[16 * SW_P];
    __shared__ __align__(16) float sWp[4 * 16 * SWP_C];  // w partials per wave

    const int tid = threadIdx.x;
    const int w = tid >> 6;
    const int l = tid & 63;
    const int i16 = l & 15, q4 = l >> 4, h2 = l >> 5, sc = q4 & 1;

    // ---------------- hoisted weight fragments (quarter per wave) ----------
    f16x8 w2a[4][2];   // A-stage A-op: W2^T[e=i16+16(4w+t)][k=8q4+j+32ch]
    #pragma unroll
    for (int t = 0; t < 4; ++t)
        #pragma unroll
        for (int ch = 0; ch < 2; ++ch)
            #pragma unroll
            for (int j = 0; j < 8; ++j)
                w2a[t][ch][j] = (f16)W2g[(8*q4 + j + 32*ch)*256 + i16 + 16*(4*w + t)];

    f16x8 w2r[8];      // r-stage A-op: W2[n=i16+16w][e=8q4+j+32ch]
    #pragma unroll
    for (int ch = 0; ch < 8; ++ch)
        #pragma unroll
        for (int j = 0; j < 8; ++j)
            w2r[ch][j] = (f16)W2g[(i16 + 16*w)*256 + 8*q4 + j + 32*ch];

    f16x8 w1h;         // H-stage A-op: W1^T[n=i16+16w][x=8q4+j], zero-pad k>=16
    #pragma unroll
    for (int j = 0; j < 8; ++j) {
        int k = 8*q4 + j;
        w1h[j] = (k < 16) ? (f16)W1g[k*64 + i16 + 16*w] : (f16)0.0f;
    }

    f16x8 w1q[2];      // q-stage A-op: W1[i=i16][n=8q4+j+32ch]
    #pragma unroll
    for (int ch = 0; ch < 2; ++ch)
        #pragma unroll
        for (int j = 0; j < 8; ++j)
            w1q[ch][j] = (f16)W1g[i16*64 + 8*q4 + j + 32*ch];

    float b2v[4][4];   // b2[e = 16*(4w+t) + 4q4+reg]
    #pragma unroll
    for (int t = 0; t < 4; ++t)
        #pragma unroll
        for (int reg = 0; reg < 4; ++reg)
            b2v[t][reg] = b2g[16*(4*w + t) + 4*q4 + reg];
    float b1v[4];      // b1[n = 16w + 4q4+reg]
    #pragma unroll
    for (int reg = 0; reg < 4; ++reg) b1v[reg] = b1g[16*w + 4*q4 + reg];

    // ---------------- RK4 state: thread owns point tid>>4, vals 2g16.. ----
    const int pb = blockIdx.x * 16;
    const int p_cmb = tid >> 4;            // == 4w + q4
    const int g16 = tid & 15;
    f32x2 zc, ar;
    {
        int pg = (pb + p_cmb < B) ? (pb + p_cmb) : (B - 1);
        zc = *(const f32x2*)&zin[pg*32 + 2*g16];
        *(f32x2*)&sZI[p_cmb*SZ_P + 2*g16] = zc;
    }
    __syncthreads();

    const float tv = tg[0];
    const int nst = nsg[0];
    const float dt = tv / (float)nst;

    const int xmask = (q4 >= 2) ? 0 : -1;

    #pragma unroll 1
    for (int st = 0; st < nst; ++st) {
        #pragma unroll 1
        for (int s = 0; s < 4; ++s) {
            // ---- per-eval x,v loads (lane p = i16) ----
            float vreg[16];
            u16x8 xf;
            {
                f32x4 xa = *(const f32x4*)&sZI[i16*SZ_P + 8*sc];
                f32x4 xb = *(const f32x4*)&sZI[i16*SZ_P + 8*sc + 4];
                xf.v2[0] = pk2(xa[0], xa[1]);
                xf.v2[1] = pk2(xa[2], xa[3]);
                xf.v2[2] = pk2(xb[0], xb[1]);
                xf.v2[3] = pk2(xb[2], xb[3]);
                #pragma unroll
                for (int jp = 0; jp < 4; ++jp) xf.i32[jp] &= xmask;
                #pragma unroll
                for (int m = 0; m < 4; ++m) {
                    f32x4 v4 = *(const f32x4*)&sZI[i16*SZ_P + 16 + 4*m];
                    #pragma unroll
                    for (int j = 0; j < 4; ++j) vreg[4*m + j] = v4[j];
                }
            }
            // ======== H: lane: point i16, n=16w+4q4+reg ========
            float dreg[4];
            {
                f32x4 hc = {0.f, 0.f, 0.f, 0.f};
                hc = __builtin_amdgcn_mfma_f32_16x16x32_f16(w1h, xf.v8, hc, 0, 0, 0);
                float hv[4];
                #pragma unroll
                for (int reg = 0; reg < 4; ++reg) {
                    hv[reg] = fastTanh(hc[reg] + b1v[reg]);
                    dreg[reg] = hv[reg]*hv[reg] - 1.0f;
                }
                u16x4 hv4;
                hv4.v2[0] = pk2(hv[0], hv[1]);
                hv4.v2[1] = pk2(hv[2], hv[3]);
                *(f16x4*)&sHT[i16*SH_P + 16*w + 4*q4] = hv4.v4;
            }
            __syncthreads();   // B1: h ready
            // ======== A: lane: point i16, e=16(4w+t)+4q4+reg; + w partials ========
            {
                f16x8 hf0 = *(const f16x8*)&sHT[i16*SH_P + 8*q4];
                f16x8 hf1 = *(const f16x8*)&sHT[i16*SH_P + 8*q4 + 32];
                float pw[4] = {0.f, 0.f, 0.f, 0.f};
                #pragma unroll
                for (int t = 0; t < 4; ++t) {
                    f32x4 ac = {0.f, 0.f, 0.f, 0.f};
                    ac = __builtin_amdgcn_mfma_f32_16x16x32_f16(w2a[t][0], hf0, ac, 0, 0, 0);
                    ac = __builtin_amdgcn_mfma_f32_16x16x32_f16(w2a[t][1], hf1, ac, 0, 0, 0);
                    float a0 = ac[0] + b2v[t][0], a1 = ac[1] + b2v[t][1];
                    float a2 = ac[2] + b2v[t][2], a3 = ac[3] + b2v[t][3];
                    float vv = vreg[4*w + t];
                    pw[0] += vv * a0; pw[1] += vv * a1;
                    pw[2] += vv * a2; pw[3] += vv * a3;
                    u16x4 av;
                    av.v2[0] = pk2(a0, a1);
                    av.v2[1] = pk2(a2, a3);
                    *(f16x4*)&sAG[i16*SAG_P + 24*(4*w + t) + 4*q4] = av.v4;
                }
                f32x4 pwv = {pw[0], pw[1], pw[2], pw[3]};
                *(f32x4*)&sWp[(w*16 + i16)*SWP_C + 4*q4] = pwv;
            }
            __syncthreads();   // B2: A + w partials ready
            // ======== AAT (2 pair-MFMAs/wave) -> G^T over A region ========
            #pragma unroll
            for (int u0 = 0; u0 < 2; ++u0) {
                int u = 2*w + u0;
                int pt = 2*u + sc;
                f16x8 af = *(const f16x8*)&sAG[pt*SAG_P + 24*i16 + 8*h2];
                f32x16 gz = {0.0f};
                f32x16 gacc = __builtin_amdgcn_mfma_f32_32x32x16_f16(af, af, gz, 0, 0, 0);
                float gv[8];
                #pragma unroll
                for (int rr = 0; rr < 4; ++rr) {
                    int a0 = 4*h2 + rr;
                    int a1 = 8 + 4*h2 + rr;
                    gv[rr]     = gacc[rr + 8*sc]     + ((i16 == a0) ? 1.0f : 0.0f);
                    gv[4 + rr] = gacc[rr + 4 + 8*sc] + ((i16 == a1) ? 1.0f : 0.0f);
                }
                u16x4 g0, g1;
                g0.v2[0] = pk2(gv[0], gv[1]); g0.v2[1] = pk2(gv[2], gv[3]);
                g1.v2[0] = pk2(gv[4], gv[5]); g1.v2[1] = pk2(gv[6], gv[7]);
                *(f16x4*)&sAG[pt*SAG_P + 24*i16 + 4*h2]     = g0.v4;
                *(f16x4*)&sAG[pt*SAG_P + 24*i16 + 8 + 4*h2] = g1.v4;
            }
            // ======== r: lane: point i16, n=16w+4q4+reg ========
            {
                float wv[8];
                {
                    f32x4 s0 = *(const f32x4*)&sWp[(0*16 + i16)*SWP_C + 8*sc];
                    f32x4 s1 = *(const f32x4*)&sWp[(1*16 + i16)*SWP_C + 8*sc];
                    f32x4 s2 = *(const f32x4*)&sWp[(2*16 + i16)*SWP_C + 8*sc];
                    f32x4 s3 = *(const f32x4*)&sWp[(3*16 + i16)*SWP_C + 8*sc];
                    f32x4 t0 = *(const f32x4*)&sWp[(0*16 + i16)*SWP_C + 8*sc + 4];
                    f32x4 t1 = *(const f32x4*)&sWp[(1*16 + i16)*SWP_C + 8*sc + 4];
                    f32x4 t2 = *(const f32x4*)&sWp[(2*16 + i16)*SWP_C + 8*sc + 4];
                    f32x4 t3 = *(const f32x4*)&sWp[(3*16 + i16)*SWP_C + 8*sc + 4];
                    #pragma unroll
                    for (int j = 0; j < 4; ++j) {
                        wv[j]     = s0[j] + s1[j] + s2[j] + s3[j];
                        wv[4 + j] = t0[j] + t1[j] + t2[j] + t3[j];
                    }
                }
                f16x2 wfp[4];
                #pragma unroll
                for (int jp = 0; jp < 4; ++jp) wfp[jp] = pk2(wv[2*jp], wv[2*jp + 1]);
                f32x4 racc = {0.f, 0.f, 0.f, 0.f};
                #pragma unroll
                for (int ch = 0; ch < 8; ++ch) {
                    f16 vvh = (f16)vreg[2*ch + (q4 >> 1)];
                    f16x2 vv2; vv2.x = vvh; vv2.y = vvh;
                    u16x8 uf;
                    #pragma unroll
                    for (int jp = 0; jp < 4; ++jp) uf.v2[jp] = vv2 * wfp[jp];
                    racc = __builtin_amdgcn_mfma_f32_16x16x32_f16(w2r[ch], uf.v8, racc, 0, 0, 0);
                }
                u16x4 tv4;
                tv4.v2[0] = pk2(dreg[0]*racc[0], dreg[1]*racc[1]);
                tv4.v2[1] = pk2(dreg[2]*racc[2], dreg[3]*racc[3]);
                *(f16x4*)&sHT[i16*SH_P + 16*w + 4*q4] = tv4.v4;   // t overwrites h
            }
            __syncthreads();   // B4: t ready (G/aug wave-private from here)
            // ======== q (per wave, own 4 points): aug_i = sum_n W1[i][n] t_n ====
            {
                int ptq = 4*w + (i16 & 3);
                f16x8 tb0 = *(const f16x8*)&sHT[ptq*SH_P + 8*q4];
                f16x8 tb1 = *(const f16x8*)&sHT[ptq*SH_P + 8*q4 + 32];
                f32x4 qa = {0.f, 0.f, 0.f, 0.f};
                qa = __builtin_amdgcn_mfma_f32_16x16x32_f16(w1q[0], tb0, qa, 0, 0, 0);
                qa = __builtin_amdgcn_mfma_f32_16x16x32_f16(w1q[1], tb1, qa, 0, 0, 0);
                if (i16 < 4) {
                    #pragma unroll
                    for (int reg = 0; reg < 4; ++reg)
                        sAG[(4*w + i16)*SAG_P + 24*(4*q4 + reg) + 16] = (f16)qa[reg];
                }
            }
            // ======== solve G y = aug; point 4w+q4, lane i16 = row (GJ) ========
            {
                const int psl = 4*w + q4;
                float R[17];
                {
                    const f16* rp = &sAG[psl*SAG_P + 24*i16];
                    f16x8 ra = *(const f16x8*)&rp[0];
                    f16x8 rb = *(const f16x8*)&rp[8];
                    #pragma unroll
                    for (int j = 0; j < 8; ++j) { R[j] = (float)ra[j]; R[8+j] = (float)rb[j]; }
                    R[16] = (float)rp[16];
                }
                float myinv = 1.0f;
                fe_all<0>(R, i16, myinv);
                sKV[psl*SW_P + i16] = R[16] * myinv;
            }
            // (no barrier: combine reads only this wave's points; DS in-order)
            // ======== RK4 combine ========
            {
                f32x2 kk;
                if (g16 < 8) kk = *(const f32x2*)&sZI[p_cmb*SZ_P + 16 + 2*g16];
                else         kk = *(const f32x2*)&sKV[p_cmb*SW_P + 2*(g16 - 8)];
                if (s == 0) ar = kk;
                else {
                    float wgt = (s == 3) ? 1.0f : 2.0f;
                    ar.x += wgt * kk.x; ar.y += wgt * kk.y;
                }
                f32x2 zi;
                if (s < 3) {
                    float alpha = (s < 2) ? (0.5f * dt) : dt;
                    zi.x = zc.x + alpha * kk.x; zi.y = zc.y + alpha * kk.y;
                } else {
                    float c6 = dt / 6.0f;
                    zc.x += c6 * ar.x; zc.y += c6 * ar.y;
                    zi = zc;
                }
                *(f32x2*)&sZI[p_cmb*SZ_P + 2*g16] = zi;
            }
            __syncthreads();   // B6: zI ready for next eval
        }
    }
    if (pb + p_cmb < B)
        *(f32x2*)&outg[(pb + p_cmb)*32 + 2*g16] = zc;
}

extern "C" void kernel_launch(void* const* d_in, const int* in_sizes, int n_in,
                              void* d_out, int out_size, void* d_ws, size_t ws_size,
                              hipStream_t stream) {
    (void)n_in; (void)d_ws; (void)ws_size; (void)out_size;
    const float* z  = (const float*)d_in[0];
    const float* t  = (const float*)d_in[1];
    const float* W1 = (const float*)d_in[2];
    const float* b1 = (const float*)d_in[3];
    const float* W2 = (const float*)d_in[4];
    const float* b2 = (const float*)d_in[5];
    const int*   ns = (const int*)d_in[6];
    float* out = (float*)d_out;
    const int B = in_sizes[0] / 32;
    int grid = (B + 15) / 16;
    hipLaunchKernelGGL(geo_kernel, dim3(grid), dim3(256), 0, stream,
                       z, t, W1, b1, W2, b2, ns, out, B);
}

// Round 9
// 250.464 us; speedup vs baseline: 1.4327x; 1.0541x over previous
//
#include <hip/hip_runtime.h>
#include <math.h>

// v8: v7 with the solve's 152 ds_swizzle broadcasts replaced by DPP
// row_newbcast (ctrl 0x150|K, gfx90a+): broadcast lane K within each 16-lane
// row, on the VALU pipe. Removes 80% of per-eval DS ops (the per-CU-shared
// DS pipe was ~60% busy; solve round chain 100 -> ~20 cyc). All other
// structure identical to v7 (passing, absmax 0.0156).

typedef _Float16 f16;
typedef _Float16 f16x2 __attribute__((ext_vector_type(2)));
typedef _Float16 f16x4 __attribute__((ext_vector_type(4)));
typedef _Float16 f16x8 __attribute__((ext_vector_type(8)));
typedef __fp16 h16x2 __attribute__((ext_vector_type(2)));   // builtin return type
typedef float f32x2 __attribute__((ext_vector_type(2)));
typedef float f32x4 __attribute__((ext_vector_type(4)));
typedef float f32x16 __attribute__((ext_vector_type(16)));

#define SAG_P 392   // f16 point stride; row stride 24, aug col at 16
#define SZ_P  36    // f32
#define SH_P  72    // f16
#define SW_P  20    // f32
#define SWP_C 20    // f32 stride of sWp per (wave,point)

__device__ __forceinline__ float fastTanh(float x) {
    float e = exp2f(x * 2.885390081777927f);
    return 1.0f - 2.0f * __builtin_amdgcn_rcpf(1.0f + e);
}

__device__ __forceinline__ f16x2 pk2(float a, float b) {
    h16x2 p = __builtin_amdgcn_cvt_pkrtz(a, b);
    return __builtin_bit_cast(f16x2, p);
}

typedef union { f16x4 v4; f16x2 v2[2]; } u16x4;
typedef union { f16x8 v8; f16x2 v2[4]; int i32[4]; } u16x8;

// broadcast lane K of each 16-lane row via DPP row_newbcast (VALU, no DS)
template<int K>
__device__ __forceinline__ float bcf(float x) {
    int v = __builtin_amdgcn_mov_dpp(__builtin_bit_cast(int, x),
                                     0x150 | K, 0xf, 0xf, false);
    return __builtin_bit_cast(float, v);
}

// Gauss-Jordan elimination, row-per-lane (16 lanes/point), DPP broadcasts.
template<int K>
__device__ __forceinline__ void fe_all(float (&R)[17], const int i16, float &myinv) {
    if constexpr (K < 16) {
        float pvk = bcf<K>(R[K]);
        float pinv = __builtin_amdgcn_rcpf(pvk);
        if (i16 == K) myinv = pinv;
        float f = (i16 == K) ? 0.0f : R[K] * pinv;
        #pragma unroll
        for (int j = K + 1; j <= 16; ++j) {
            float pv = bcf<K>(R[j]);
            R[j] -= f * pv;
        }
        fe_all<K + 1>(R, i16, myinv);
    }
}

__global__ __launch_bounds__(256, 1)
void geo_kernel(const float* __restrict__ zin, const float* __restrict__ tg,
                const float* __restrict__ W1g, const float* __restrict__ b1g,
                const float* __restrict__ W2g, const float* __restrict__ b2g,
                const int* __restrict__ nsg, float* __restrict__ outg, int B)
{
    __shared__ __align__(16) f16   sAG[16 * SAG_P];      // A, then G (+aug)
    __shared__ __align__(16) f16   sHT[16 * SH_P];       // h, later t
    __shared__ __align__(16) float sZI[16 * SZ_P];
    __shared__ __align__(16) float sKV[16 * SW_P];
    __shared__ __align__(16) float sWp[4 * 16 * SWP_C];  // w partials per wave

    const int tid = threadIdx.x;
    const int w = tid >> 6;
    const int l = tid & 63;
    const int i16 = l & 15, q4 = l >> 4, h2 = l >> 5, sc = q4 & 1;

    // ---------------- hoisted weight fragments (quarter per wave) ----------
    f16x8 w2a[4][2];   // A-stage A-op: W2^T[e=i16+16(4w+t)][k=8q4+j+32ch]
    #pragma unroll
    for (int t = 0; t < 4; ++t)
        #pragma unroll
        for (int ch = 0; ch < 2; ++ch)
            #pragma unroll
            for (int j = 0; j < 8; ++j)
                w2a[t][ch][j] = (f16)W2g[(8*q4 + j + 32*ch)*256 + i16 + 16*(4*w + t)];

    f16x8 w2r[8];      // r-stage A-op: W2[n=i16+16w][e=8q4+j+32ch]
    #pragma unroll
    for (int ch = 0; ch < 8; ++ch)
        #pragma unroll
        for (int j = 0; j < 8; ++j)
            w2r[ch][j] = (f16)W2g[(i16 + 16*w)*256 + 8*q4 + j + 32*ch];

    f16x8 w1h;         // H-stage A-op: W1^T[n=i16+16w][x=8q4+j], zero-pad k>=16
    #pragma unroll
    for (int j = 0; j < 8; ++j) {
        int k = 8*q4 + j;
        w1h[j] = (k < 16) ? (f16)W1g[k*64 + i16 + 16*w] : (f16)0.0f;
    }

    f16x8 w1q[2];      // q-stage A-op: W1[i=i16][n=8q4+j+32ch]
    #pragma unroll
    for (int ch = 0; ch < 2; ++ch)
        #pragma unroll
        for (int j = 0; j < 8; ++j)
            w1q[ch][j] = (f16)W1g[i16*64 + 8*q4 + j + 32*ch];

    float b2v[4][4];   // b2[e = 16*(4w+t) + 4q4+reg]
    #pragma unroll
    for (int t = 0; t < 4; ++t)
        #pragma unroll
        for (int reg = 0; reg < 4; ++reg)
            b2v[t][reg] = b2g[16*(4*w + t) + 4*q4 + reg];
    float b1v[4];      // b1[n = 16w + 4q4+reg]
    #pragma unroll
    for (int reg = 0; reg < 4; ++reg) b1v[reg] = b1g[16*w + 4*q4 + reg];

    // ---------------- RK4 state: thread owns point tid>>4, vals 2g16.. ----
    const int pb = blockIdx.x * 16;
    const int p_cmb = tid >> 4;            // == 4w + q4
    const int g16 = tid & 15;
    f32x2 zc, ar;
    {
        int pg = (pb + p_cmb < B) ? (pb + p_cmb) : (B - 1);
        zc = *(const f32x2*)&zin[pg*32 + 2*g16];
        *(f32x2*)&sZI[p_cmb*SZ_P + 2*g16] = zc;
    }
    __syncthreads();

    const float tv = tg[0];
    const int nst = nsg[0];
    const float dt = tv / (float)nst;

    const int xmask = (q4 >= 2) ? 0 : -1;

    #pragma unroll 1
    for (int st = 0; st < nst; ++st) {
        #pragma unroll 1
        for (int s = 0; s < 4; ++s) {
            // ---- per-eval x,v loads (lane p = i16) ----
            float vreg[16];
            u16x8 xf;
            {
                f32x4 xa = *(const f32x4*)&sZI[i16*SZ_P + 8*sc];
                f32x4 xb = *(const f32x4*)&sZI[i16*SZ_P + 8*sc + 4];
                xf.v2[0] = pk2(xa[0], xa[1]);
                xf.v2[1] = pk2(xa[2], xa[3]);
                xf.v2[2] = pk2(xb[0], xb[1]);
                xf.v2[3] = pk2(xb[2], xb[3]);
                #pragma unroll
                for (int jp = 0; jp < 4; ++jp) xf.i32[jp] &= xmask;
                #pragma unroll
                for (int m = 0; m < 4; ++m) {
                    f32x4 v4 = *(const f32x4*)&sZI[i16*SZ_P + 16 + 4*m];
                    #pragma unroll
                    for (int j = 0; j < 4; ++j) vreg[4*m + j] = v4[j];
                }
            }
            // ======== H: lane: point i16, n=16w+4q4+reg ========
            float dreg[4];
            {
                f32x4 hc = {0.f, 0.f, 0.f, 0.f};
                hc = __builtin_amdgcn_mfma_f32_16x16x32_f16(w1h, xf.v8, hc, 0, 0, 0);
                float hv[4];
                #pragma unroll
                for (int reg = 0; reg < 4; ++reg) {
                    hv[reg] = fastTanh(hc[reg] + b1v[reg]);
                    dreg[reg] = hv[reg]*hv[reg] - 1.0f;
                }
                u16x4 hv4;
                hv4.v2[0] = pk2(hv[0], hv[1]);
                hv4.v2[1] = pk2(hv[2], hv[3]);
                *(f16x4*)&sHT[i16*SH_P + 16*w + 4*q4] = hv4.v4;
            }
            __syncthreads();   // B1: h ready
            // ======== A: lane: point i16, e=16(4w+t)+4q4+reg; + w partials ========
            {
                f16x8 hf0 = *(const f16x8*)&sHT[i16*SH_P + 8*q4];
                f16x8 hf1 = *(const f16x8*)&sHT[i16*SH_P + 8*q4 + 32];
                float pw[4] = {0.f, 0.f, 0.f, 0.f};
                #pragma unroll
                for (int t = 0; t < 4; ++t) {
                    f32x4 ac = {0.f, 0.f, 0.f, 0.f};
                    ac = __builtin_amdgcn_mfma_f32_16x16x32_f16(w2a[t][0], hf0, ac, 0, 0, 0);
                    ac = __builtin_amdgcn_mfma_f32_16x16x32_f16(w2a[t][1], hf1, ac, 0, 0, 0);
                    float a0 = ac[0] + b2v[t][0], a1 = ac[1] + b2v[t][1];
                    float a2 = ac[2] + b2v[t][2], a3 = ac[3] + b2v[t][3];
                    float vv = vreg[4*w + t];
                    pw[0] += vv * a0; pw[1] += vv * a1;
                    pw[2] += vv * a2; pw[3] += vv * a3;
                    u16x4 av;
                    av.v2[0] = pk2(a0, a1);
                    av.v2[1] = pk2(a2, a3);
                    *(f16x4*)&sAG[i16*SAG_P + 24*(4*w + t) + 4*q4] = av.v4;
                }
                f32x4 pwv = {pw[0], pw[1], pw[2], pw[3]};
                *(f32x4*)&sWp[(w*16 + i16)*SWP_C + 4*q4] = pwv;
            }
            __syncthreads();   // B2: A + w partials ready
            // ======== AAT (2 pair-MFMAs/wave) -> G^T over A region ========
            #pragma unroll
            for (int u0 = 0; u0 < 2; ++u0) {
                int u = 2*w + u0;
                int pt = 2*u + sc;
                f16x8 af = *(const f16x8*)&sAG[pt*SAG_P + 24*i16 + 8*h2];
                f32x16 gz = {0.0f};
                f32x16 gacc = __builtin_amdgcn_mfma_f32_32x32x16_f16(af, af, gz, 0, 0, 0);
                float gv[8];
                #pragma unroll
                for (int rr = 0; rr < 4; ++rr) {
                    int a0 = 4*h2 + rr;
                    int a1 = 8 + 4*h2 + rr;
                    gv[rr]     = gacc[rr + 8*sc]     + ((i16 == a0) ? 1.0f : 0.0f);
                    gv[4 + rr] = gacc[rr + 4 + 8*sc] + ((i16 == a1) ? 1.0f : 0.0f);
                }
                u16x4 g0, g1;
                g0.v2[0] = pk2(gv[0], gv[1]); g0.v2[1] = pk2(gv[2], gv[3]);
                g1.v2[0] = pk2(gv[4], gv[5]); g1.v2[1] = pk2(gv[6], gv[7]);
                *(f16x4*)&sAG[pt*SAG_P + 24*i16 + 4*h2]     = g0.v4;
                *(f16x4*)&sAG[pt*SAG_P + 24*i16 + 8 + 4*h2] = g1.v4;
            }
            // ======== r: lane: point i16, n=16w+4q4+reg ========
            {
                float wv[8];
                {
                    f32x4 s0 = *(const f32x4*)&sWp[(0*16 + i16)*SWP_C + 8*sc];
                    f32x4 s1 = *(const f32x4*)&sWp[(1*16 + i16)*SWP_C + 8*sc];
                    f32x4 s2 = *(const f32x4*)&sWp[(2*16 + i16)*SWP_C + 8*sc];
                    f32x4 s3 = *(const f32x4*)&sWp[(3*16 + i16)*SWP_C + 8*sc];
                    f32x4 t0 = *(const f32x4*)&sWp[(0*16 + i16)*SWP_C + 8*sc + 4];
                    f32x4 t1 = *(const f32x4*)&sWp[(1*16 + i16)*SWP_C + 8*sc + 4];
                    f32x4 t2 = *(const f32x4*)&sWp[(2*16 + i16)*SWP_C + 8*sc + 4];
                    f32x4 t3 = *(const f32x4*)&sWp[(3*16 + i16)*SWP_C + 8*sc + 4];
                    #pragma unroll
                    for (int j = 0; j < 4; ++j) {
                        wv[j]     = s0[j] + s1[j] + s2[j] + s3[j];
                        wv[4 + j] = t0[j] + t1[j] + t2[j] + t3[j];
                    }
                }
                f16x2 wfp[4];
                #pragma unroll
                for (int jp = 0; jp < 4; ++jp) wfp[jp] = pk2(wv[2*jp], wv[2*jp + 1]);
                f32x4 racc = {0.f, 0.f, 0.f, 0.f};
                #pragma unroll
                for (int ch = 0; ch < 8; ++ch) {
                    f16 vvh = (f16)vreg[2*ch + (q4 >> 1)];
                    f16x2 vv2; vv2.x = vvh; vv2.y = vvh;
                    u16x8 uf;
                    #pragma unroll
                    for (int jp = 0; jp < 4; ++jp) uf.v2[jp] = vv2 * wfp[jp];
                    racc = __builtin_amdgcn_mfma_f32_16x16x32_f16(w2r[ch], uf.v8, racc, 0, 0, 0);
                }
                u16x4 tv4;
                tv4.v2[0] = pk2(dreg[0]*racc[0], dreg[1]*racc[1]);
                tv4.v2[1] = pk2(dreg[2]*racc[2], dreg[3]*racc[3]);
                *(f16x4*)&sHT[i16*SH_P + 16*w + 4*q4] = tv4.v4;   // t overwrites h
            }
            __syncthreads();   // B4: t ready (G/aug wave-private from here)
            // ======== q (per wave, own 4 points): aug_i = sum_n W1[i][n] t_n ====
            {
                int ptq = 4*w + (i16 & 3);
                f16x8 tb0 = *(const f16x8*)&sHT[ptq*SH_P + 8*q4];
                f16x8 tb1 = *(const f16x8*)&sHT[ptq*SH_P + 8*q4 + 32];
                f32x4 qa = {0.f, 0.f, 0.f, 0.f};
                qa = __builtin_amdgcn_mfma_f32_16x16x32_f16(w1q[0], tb0, qa, 0, 0, 0);
                qa = __builtin_amdgcn_mfma_f32_16x16x32_f16(w1q[1], tb1, qa, 0, 0, 0);
                if (i16 < 4) {
                    #pragma unroll
                    for (int reg = 0; reg < 4; ++reg)
                        sAG[(4*w + i16)*SAG_P + 24*(4*q4 + reg) + 16] = (f16)qa[reg];
                }
            }
            // ======== solve G y = aug; point 4w+q4, lane i16 = row (GJ, DPP) =====
            {
                const int psl = 4*w + q4;
                float R[17];
                {
                    const f16* rp = &sAG[psl*SAG_P + 24*i16];
                    f16x8 ra = *(const f16x8*)&rp[0];
                    f16x8 rb = *(const f16x8*)&rp[8];
                    #pragma unroll
                    for (int j = 0; j < 8; ++j) { R[j] = (float)ra[j]; R[8+j] = (float)rb[j]; }
                    R[16] = (float)rp[16];
                }
                float myinv = 1.0f;
                fe_all<0>(R, i16, myinv);
                sKV[psl*SW_P + i16] = R[16] * myinv;
            }
            // (no barrier: combine reads only this wave's points; DS in-order)
            // ======== RK4 combine ========
            {
                f32x2 kk;
                if (g16 < 8) kk = *(const f32x2*)&sZI[p_cmb*SZ_P + 16 + 2*g16];
                else         kk = *(const f32x2*)&sKV[p_cmb*SW_P + 2*(g16 - 8)];
                if (s == 0) ar = kk;
                else {
                    float wgt = (s == 3) ? 1.0f : 2.0f;
                    ar.x += wgt * kk.x; ar.y += wgt * kk.y;
                }
                f32x2 zi;
                if (s < 3) {
                    float alpha = (s < 2) ? (0.5f * dt) : dt;
                    zi.x = zc.x + alpha * kk.x; zi.y = zc.y + alpha * kk.y;
                } else {
                    float c6 = dt / 6.0f;
                    zc.x += c6 * ar.x; zc.y += c6 * ar.y;
                    zi = zc;
                }
                *(f32x2*)&sZI[p_cmb*SZ_P + 2*g16] = zi;
            }
            __syncthreads();   // B6: zI ready for next eval
        }
    }
    if (pb + p_cmb < B)
        *(f32x2*)&outg[(pb + p_cmb)*32 + 2*g16] = zc;
}

extern "C" void kernel_launch(void* const* d_in, const int* in_sizes, int n_in,
                              void* d_out, int out_size, void* d_ws, size_t ws_size,
                              hipStream_t stream) {
    (void)n_in; (void)d_ws; (void)ws_size; (void)out_size;
    const float* z  = (const float*)d_in[0];
    const float* t  = (const float*)d_in[1];
    const float* W1 = (const float*)d_in[2];
    const float* b1 = (const float*)d_in[3];
    const float* W2 = (const float*)d_in[4];
    const float* b2 = (const float*)d_in[5];
    const int*   ns = (const int*)d_in[6];
    float* out = (float*)d_out;
    const int B = in_sizes[0] / 32;
    int grid = (B + 15) / 16;
    hipLaunchKernelGGL(geo_kernel, dim3(grid), dim3(256), 0, stream,
                       z, t, W1, b1, W2, b2, ns, out, B);
}